// Round 15
// baseline (556.284 us; speedup 1.0000x reference)
//
#include <hip/hip_runtime.h>
#include <hip/hip_bf16.h>

#define B_ 4
#define N_ 512
#define D_ 128
#define LOG2E 1.4426950408889634f

typedef __attribute__((ext_vector_type(8))) short bf16x8;
typedef __attribute__((ext_vector_type(4))) short s16x4;
typedef __attribute__((ext_vector_type(4))) float f32x4;
typedef __attribute__((ext_vector_type(16))) float f32x16;

__device__ __forceinline__ f32x4 mfma16(bf16x8 a, bf16x8 b, f32x4 c) {
    return __builtin_amdgcn_mfma_f32_16x16x32_bf16(a, b, c, 0, 0, 0);
}
__device__ __forceinline__ f32x16 mfma32(bf16x8 a, bf16x8 b, f32x16 c) {
    return __builtin_amdgcn_mfma_f32_32x32x16_bf16(a, b, c, 0, 0, 0);
}
__device__ __forceinline__ short bf16b(float x) {
    __hip_bfloat16 h = __float2bfloat16(x);
    return *reinterpret_cast<short*>(&h);
}
__device__ __forceinline__ float b2f(short s) {
    unsigned u = ((unsigned)(unsigned short)s) << 16;
    union { unsigned u; float f; } c; c.u = u; return c.f;
}

// ---------------- prep A (merged): weights fold + posw + qkv ----------------
__global__ void prep_misc_kernel(const float* __restrict__ aW1, const float* __restrict__ aW2,
                                 const float* __restrict__ pW2, const float* __restrict__ pb2,
                                 const float* __restrict__ ab1, const float* __restrict__ pos,
                                 const float* __restrict__ pW1, const float* __restrict__ x,
                                 const float* __restrict__ Wqkv, const float* __restrict__ bqkv,
                                 __hip_bfloat16* __restrict__ aW2T, __hip_bfloat16* __restrict__ pW2T,
                                 __hip_bfloat16* __restrict__ W12T, float* __restrict__ cvec,
                                 float* __restrict__ posw,
                                 float* __restrict__ q, float* __restrict__ k,
                                 short* __restrict__ vb_t) {
    const int bid = blockIdx.x;
    const int tid = threadIdx.x;
    if (bid < 128) {
        int idx = bid * 256 + tid;
        {
            int n = idx >> 8, k2 = idx & 255;
            aW2T[idx] = __float2bfloat16(aW2[k2 * 128 + n] * LOG2E);
        }
        if (idx < 128 * 64) {
            int n = idx >> 6, k2 = idx & 63;
            pW2T[idx] = __float2bfloat16(pW2[k2 * 128 + n]);
        }
        if (idx < 256 * 64) {
            int n = idx >> 6, h = idx & 63;
            float s = 0.f;
#pragma unroll 8
            for (int d = 0; d < 128; ++d) s += pW2[h * 128 + d] * aW1[d * 256 + n];
            W12T[idx] = __float2bfloat16(s);
        }
        if (idx < 256) {
            float s = ab1[idx];
#pragma unroll 8
            for (int d = 0; d < 128; ++d) s += pb2[d] * aW1[d * 256 + idx];
            cvec[idx] = s;
        }
    } else if (bid < 256) {
        int i4 = (bid - 128) * 256 + tid;
        int t = i4 >> 4, h4 = (i4 & 15) * 4;
        float p0 = pos[t * 3 + 0], p1 = pos[t * 3 + 1], p2 = pos[t * 3 + 2];
#pragma unroll
        for (int e = 0; e < 4; ++e) {
            int h = h4 + e;
            posw[t * 64 + h] = p0 * pW1[h] + p1 * pW1[64 + h] + p2 * pW1[128 + h];
        }
    } else {
        int idx = (bid - 256) * 256 + tid;
        int m = idx % 384;
        int g = idx / 384;
        int bn0 = g * 16;
        int b = bn0 >> 9, n0 = bn0 & (N_ - 1);
        const float* xp = x + (b * D_) * N_ + n0;
        float bias = bqkv[m];
        float acc[16];
#pragma unroll
        for (int t = 0; t < 16; ++t) acc[t] = bias;
#pragma unroll 2
        for (int d = 0; d < D_; ++d) {
            float wv = Wqkv[d * 384 + m];
            const float* xr = xp + d * N_;
            float4 x0 = *(const float4*)(xr);
            float4 x1 = *(const float4*)(xr + 4);
            float4 x2 = *(const float4*)(xr + 8);
            float4 x3 = *(const float4*)(xr + 12);
            acc[0]  = fmaf(x0.x, wv, acc[0]);  acc[1]  = fmaf(x0.y, wv, acc[1]);
            acc[2]  = fmaf(x0.z, wv, acc[2]);  acc[3]  = fmaf(x0.w, wv, acc[3]);
            acc[4]  = fmaf(x1.x, wv, acc[4]);  acc[5]  = fmaf(x1.y, wv, acc[5]);
            acc[6]  = fmaf(x1.z, wv, acc[6]);  acc[7]  = fmaf(x1.w, wv, acc[7]);
            acc[8]  = fmaf(x2.x, wv, acc[8]);  acc[9]  = fmaf(x2.y, wv, acc[9]);
            acc[10] = fmaf(x2.z, wv, acc[10]); acc[11] = fmaf(x2.w, wv, acc[11]);
            acc[12] = fmaf(x3.x, wv, acc[12]); acc[13] = fmaf(x3.y, wv, acc[13]);
            acc[14] = fmaf(x3.z, wv, acc[14]); acc[15] = fmaf(x3.w, wv, acc[15]);
        }
        if (m < 256) {
            float* dst = (m < 128) ? q : k;
            int mm = m & 127;
#pragma unroll
            for (int t = 0; t < 16; ++t)
                dst[(bn0 + t) * D_ + mm] = acc[t];
        } else {
            int d = m & 127;
            float pv = pb2[d];
            int jt = n0 >> 6;
            int jr = n0 & 63;
            int rtv = jr >> 5;
            int jrr0 = jr & 31;
            int ct = d >> 5;
            int lbase = d & 31;
            size_t tilebase = (size_t)b * 65536 + (size_t)jt * 8192
                            + (size_t)((rtv * 4 + ct) * 64) * 16;
#pragma unroll
            for (int tt = 0; tt < 4; ++tt) {
                int jrr = jrr0 + tt * 4;
                int rb = 4 * (jrr >> 3);
                int hi = (jrr >> 2) & 1;
                s16x4 pk;
                pk[0] = bf16b(acc[tt * 4 + 0] + pv); pk[1] = bf16b(acc[tt * 4 + 1] + pv);
                pk[2] = bf16b(acc[tt * 4 + 2] + pv); pk[3] = bf16b(acc[tt * 4 + 3] + pv);
                *(s16x4*)(vb_t + tilebase + (size_t)(lbase + 32 * hi) * 16 + rb) = pk;
            }
        }
    }
}

// ---------------- prep B: qa = q@aW1 (fp32), ka = k@aW1 -> 16x16-tiled bf16 ----
__global__ void qka_kernel(const float* __restrict__ q, const float* __restrict__ k,
                           const float* __restrict__ aW1,
                           float* __restrict__ qa, short* __restrict__ kab_t) {
    int col = threadIdx.x;
    int bn0 = blockIdx.x * 8;
    int b = bn0 >> 9, n0 = bn0 & (N_ - 1);
    const float* qp = q + (size_t)bn0 * D_;
    const float* kp = k + (size_t)bn0 * D_;
    float aq[8], ak[8];
#pragma unroll
    for (int t = 0; t < 8; ++t) { aq[t] = 0.f; ak[t] = 0.f; }
#pragma unroll 2
    for (int d = 0; d < D_; ++d) {
        float wv = aW1[d * 256 + col];
#pragma unroll
        for (int t = 0; t < 8; ++t) {
            aq[t] = fmaf(qp[t * D_ + d], wv, aq[t]);
            ak[t] = fmaf(kp[t * D_ + d], wv, ak[t]);
        }
    }
#pragma unroll
    for (int t = 0; t < 8; ++t)
        qa[(size_t)(bn0 + t) * 256 + col] = aq[t];
    int jt = n0 >> 6;
    int mt = (n0 >> 4) & 3;
    int lg0 = (n0 >> 2) & 3;
    int w = col >> 5, nt = (col >> 4) & 1, lc = col & 15;
#pragma unroll
    for (int half = 0; half < 2; ++half) {
        int lg = lg0 + half;
        int l = lg * 16 + lc;
        s16x4 pk;
        pk[0] = bf16b(ak[half * 4 + 0]); pk[1] = bf16b(ak[half * 4 + 1]);
        pk[2] = bf16b(ak[half * 4 + 2]); pk[3] = bf16b(ak[half * 4 + 3]);
        size_t base = (((((size_t)b * 8 + jt) * 8 + w) * 2 + nt) * 4 + mt) * 256 + l * 4;
        *(s16x4*)(kab_t + base) = pk;
    }
}

// ------- main fused kernel: ONE (b,i) per 256-thread block (barrier decoupling) -------
// Wave w owns: GEMM1 n-cols 64w..64w+63; GEMM2/rpe d-cols 32w..32w+31 (both rt in-wave).
__global__ __launch_bounds__(256, 2) void fused_attn_kernel(
    const float* __restrict__ qa, const short* __restrict__ kab_t,
    const short* __restrict__ vb_t,
    const float* __restrict__ posw, const float* __restrict__ pb1,
    const __hip_bfloat16* __restrict__ pW2T, const float* __restrict__ pb2,
    const __hip_bfloat16* __restrict__ W12T, const float* __restrict__ cvec,
    const __hip_bfloat16* __restrict__ aW2T, const float* __restrict__ ab2,
    float* __restrict__ out)
{
    __shared__ __hip_bfloat16 ph_s[64][72];       // 9.2 KB
    __shared__ __hip_bfloat16 hid_s[64][264];     // 33.8 KB (gx8-swizzled cols)
    __shared__ float pwi_s[64];

    const int tid = threadIdx.x;
    const int w   = tid >> 6;     // wave 0..3
    const int l   = tid & 63;
    const int lg  = l >> 4;
    const int lc  = l & 15;
    const int l31 = l & 31;
    const int hi  = l >> 5;
    const int gx8 = ((l31 >> 2) & 3) << 3;

    // grid = 2048; XCD swizzle (2048 % 8 == 0, bijective)
    const int blk = (blockIdx.x & 7) * 256 + (blockIdx.x >> 3);
    const int b   = blk >> 9;
    const int i   = blk & (N_ - 1);

    if (tid < 64) pwi_s[tid] = posw[(size_t)(b * N_ + i) * 64 + tid] + pb1[tid];

    const int col0  = 64 * w + lc;     // GEMM1 base col (nt adds 16*nt)
    const int dcol2 = 32 * w + l31;    // GEMM2 / output channel

    float qr[4];
#pragma unroll
    for (int nt = 0; nt < 4; ++nt)
        qr[nt] = qa[(b * N_ + i) * 256 + col0 + 16 * nt] + cvec[col0 + 16 * nt];

    // ---- persistent: bw2 (64 VGPR); bwp/bw12 per-jt L2 reloads ----
    const __hip_bfloat16* a2base = aW2T + (size_t)dcol2 * 256 + 8 * hi;
    bf16x8 bw2[16];
#pragma unroll
    for (int ks = 0; ks < 16; ++ks)
        bw2[ks] = *(const bf16x8*)(a2base + 16 * ks);
    const __hip_bfloat16* ppb = pW2T + (size_t)dcol2 * 64 + 8 * hi;
    const __hip_bfloat16* p12b = W12T + (size_t)col0 * 64 + 8 * lg;

    float l_run = 0.f, o_run = 0.f;
    float vv[2][16];

    // kab_t: [b][jt][w8][nt2][mt][lane][r]; for 4-wave layout offset = nt*1024 + mt*256
    const short* ktp0 = kab_t + (size_t)b * 131072 + (2 * w) * 2048 + l * 4;
    const short* vtp0 = vb_t + (size_t)b * 65536 + (size_t)(w * 64 + l) * 16;  // + rt*4096 + jt*8192

    const int jl = tid >> 2;          // A-phase: 64 rows, 4 threads/row
    const int hb = (tid & 3) * 16;    // 16 h per thread

    // ---- prologue: A(0) + kv/vb(0) loads ----
    s16x4 vb4[2][4], kv[4][4];
#pragma unroll
    for (int rt = 0; rt < 2; ++rt)
#pragma unroll
        for (int q4 = 0; q4 < 4; ++q4)
            vb4[rt][q4] = *(const s16x4*)(vtp0 + rt * 4096 + 4 * q4);
#pragma unroll
    for (int nt = 0; nt < 4; ++nt)
#pragma unroll
        for (int mt = 0; mt < 4; ++mt)
            kv[nt][mt] = *(const s16x4*)(ktp0 + nt * 1024 + mt * 256);
    __syncthreads();   // pwi_s ready
    {
        const float* pj = posw + (size_t)(b * N_ + jl) * 64 + hb;
        float4 x0 = *(const float4*)pj;
        float4 x1 = *(const float4*)(pj + 4);
        float4 x2 = *(const float4*)(pj + 8);
        float4 x3 = *(const float4*)(pj + 12);
        float xr[16] = {x0.x,x0.y,x0.z,x0.w, x1.x,x1.y,x1.z,x1.w,
                        x2.x,x2.y,x2.z,x2.w, x3.x,x3.y,x3.z,x3.w};
        bf16x8 t0, t1;
#pragma unroll
        for (int h = 0; h < 8; ++h) {
            t0[h] = bf16b(fmaxf(pwi_s[hb + h] - xr[h], 0.f));
            t1[h] = bf16b(fmaxf(pwi_s[hb + 8 + h] - xr[8 + h], 0.f));
        }
        *(bf16x8*)(&ph_s[jl][hb]) = t0;
        *(bf16x8*)(&ph_s[jl][hb + 8]) = t1;
    }
    __syncthreads();

    for (int jt = 0; jt < 8; ++jt) {
        // ---- per-jt weight reloads (jt-invariant addresses, L2-hot) ----
        bf16x8 bwp[4], bw12[4][2];
#pragma unroll
        for (int ks = 0; ks < 4; ++ks)
            bwp[ks] = *(const bf16x8*)(ppb + 16 * ks);
#pragma unroll
        for (int nt = 0; nt < 4; ++nt)
#pragma unroll
            for (int k2 = 0; k2 < 2; ++k2)
                bw12[nt][k2] = *(const bf16x8*)(p12b + nt * 1024 + k2 * 32);

        // ================= R1: rpe (both rt) + GEMM1 (64 cols) =================
#pragma unroll
        for (int rt = 0; rt < 2; ++rt) {
            f32x16 accr = {0.f,0.f,0.f,0.f,0.f,0.f,0.f,0.f,0.f,0.f,0.f,0.f,0.f,0.f,0.f,0.f};
#pragma unroll
            for (int ks = 0; ks < 4; ++ks) {
                bf16x8 a = *(const bf16x8*)(&ph_s[32 * rt + l31][16 * ks + 8 * hi]);
                accr = mfma32(a, bwp[ks], accr);
            }
#pragma unroll
            for (int r = 0; r < 16; ++r)
                vv[rt][r] = accr[r] + b2f(vb4[rt][r >> 2][r & 3]);   // pb2 folded
        }
#pragma unroll
        for (int mt = 0; mt < 4; ++mt) {
            bf16x8 a0 = *(const bf16x8*)(&ph_s[mt * 16 + lc][8 * lg]);
            bf16x8 a1 = *(const bf16x8*)(&ph_s[mt * 16 + lc][32 + 8 * lg]);
#pragma unroll
            for (int nt = 0; nt < 4; ++nt) {
                f32x4 acc = {0.f, 0.f, 0.f, 0.f};
                acc = mfma16(a0, bw12[nt][0], acc);
                acc = mfma16(a1, bw12[nt][1], acc);
                const int colw = 64 * w + ((16 * nt + lc) ^ (8 * lg));
#pragma unroll
                for (int r = 0; r < 4; ++r) {
                    int row = mt * 16 + 4 * lg + r;
                    hid_s[row][colw] = __float2bfloat16(
                        fmaxf(acc[r] + qr[nt] - b2f(kv[nt][mt][r]), 0.f));
                }
            }
        }
        __syncthreads();

        // ====== R2: prefetch(jt+1) -> GEMM2 rt0+softmax -> rt1+softmax -> A(jt+1) ======
        const int jtn = (jt < 7) ? jt + 1 : 7;
        {
            const short* vtp = vtp0 + (size_t)jtn * 8192;
            const short* ktp = ktp0 + (size_t)jtn * 16384;
#pragma unroll
            for (int rt = 0; rt < 2; ++rt)
#pragma unroll
                for (int q4 = 0; q4 < 4; ++q4)
                    vb4[rt][q4] = *(const s16x4*)(vtp + rt * 4096 + 4 * q4);
#pragma unroll
            for (int nt = 0; nt < 4; ++nt)
#pragma unroll
                for (int mt = 0; mt < 4; ++mt)
                    kv[nt][mt] = *(const s16x4*)(ktp + nt * 1024 + mt * 256);
        }
        float4 px0, px1, px2, px3;
        if (jt < 7) {
            const float* pj = posw + (size_t)(b * N_ + jtn * 64 + jl) * 64 + hb;
            px0 = *(const float4*)pj;
            px1 = *(const float4*)(pj + 4);
            px2 = *(const float4*)(pj + 8);
            px3 = *(const float4*)(pj + 12);
        }

#pragma unroll
        for (int rt = 0; rt < 2; ++rt) {
            f32x16 Aa = {0.f,0.f,0.f,0.f,0.f,0.f,0.f,0.f,0.f,0.f,0.f,0.f,0.f,0.f,0.f,0.f};
            f32x16 Ab = {0.f,0.f,0.f,0.f,0.f,0.f,0.f,0.f,0.f,0.f,0.f,0.f,0.f,0.f,0.f,0.f};
            const short* hrow = (const short*)&hid_s[32 * rt + l31][0];
#pragma unroll
            for (int ks = 0; ks < 8; ++ks) {
                bf16x8 aa = *(const bf16x8*)(hrow + ((16 * ks + 8 * hi) ^ gx8));
                bf16x8 ab = *(const bf16x8*)(hrow + ((16 * (ks + 8) + 8 * hi) ^ gx8));
                Aa = mfma32(aa, bw2[ks], Aa);
                Ab = mfma32(ab, bw2[ks + 8], Ab);
            }
            float lp[4] = {0.f, 0.f, 0.f, 0.f};
            float op[4] = {0.f, 0.f, 0.f, 0.f};
#pragma unroll
            for (int r = 0; r < 16; ++r) {
                float e = __builtin_amdgcn_exp2f(Aa[r] + Ab[r]);
                lp[r & 3] += e;
                op[r & 3] = fmaf(e, vv[rt][r], op[r & 3]);
            }
            l_run += (lp[0] + lp[1]) + (lp[2] + lp[3]);
            o_run += (op[0] + op[1]) + (op[2] + op[3]);
        }

        // ---- A(jt+1): ph rewrite (all jt readers of ph finished before R1-end barrier) ----
        if (jt < 7) {
            float xr[16] = {px0.x,px0.y,px0.z,px0.w, px1.x,px1.y,px1.z,px1.w,
                            px2.x,px2.y,px2.z,px2.w, px3.x,px3.y,px3.z,px3.w};
            bf16x8 t0, t1;
#pragma unroll
            for (int h = 0; h < 8; ++h) {
                t0[h] = bf16b(fmaxf(pwi_s[hb + h] - xr[h], 0.f));
                t1[h] = bf16b(fmaxf(pwi_s[hb + 8 + h] - xr[8 + h], 0.f));
            }
            *(bf16x8*)(&ph_s[jl][hb]) = t0;
            *(bf16x8*)(&ph_s[jl][hb + 8]) = t1;
        }
        __syncthreads();
    }

    // ---- final: lane^32 sum (rows split across hi), write own channel ----
    float L = l_run + __shfl_xor(l_run, 32);
    float O = o_run + __shfl_xor(o_run, 32);
    if (hi == 0)
        out[((size_t)b * D_ + dcol2) * N_ + i] = O / L;
}

extern "C" void kernel_launch(void* const* d_in, const int* in_sizes, int n_in,
                              void* d_out, int out_size, void* d_ws, size_t ws_size,
                              hipStream_t stream) {
    const float* x    = (const float*)d_in[0];
    const float* pos  = (const float*)d_in[1];
    const float* Wqkv = (const float*)d_in[2];
    const float* bqkv = (const float*)d_in[3];
    const float* pW1  = (const float*)d_in[4];
    const float* pb1  = (const float*)d_in[5];
    const float* pW2  = (const float*)d_in[6];
    const float* pb2  = (const float*)d_in[7];
    const float* aW1  = (const float*)d_in[8];
    const float* ab1  = (const float*)d_in[9];
    const float* aW2  = (const float*)d_in[10];
    const float* ab2  = (const float*)d_in[11];
    float* out = (float*)d_out;

    float* q    = (float*)d_ws;
    float* k    = q  + B_ * N_ * D_;
    float* qa   = k  + B_ * N_ * D_;
    float* posw = qa + B_ * N_ * 256;
    float* cvec = posw + B_ * N_ * 64;
    short* kab_t = (short*)(cvec + 256);
    short* vb_t  = kab_t + B_ * N_ * 256;
    __hip_bfloat16* aW2T = (__hip_bfloat16*)(vb_t + B_ * N_ * D_);
    __hip_bfloat16* pW2T = aW2T + 128 * 256;
    __hip_bfloat16* W12T = pW2T + 128 * 64;

    hipLaunchKernelGGL(prep_misc_kernel, dim3(448), dim3(256), 0, stream,
                       aW1, aW2, pW2, pb2, ab1, pos, pW1, x, Wqkv, bqkv,
                       aW2T, pW2T, W12T, cvec, posw, q, k, vb_t);
    hipLaunchKernelGGL(qka_kernel, dim3(256), dim3(256), 0, stream,
                       q, k, aW1, qa, kab_t);
    hipLaunchKernelGGL(fused_attn_kernel, dim3(2048), dim3(256), 0, stream,
                       qa, kab_t, vb_t, posw, pb1, pW2T, pb2, W12T, cvec, aW2T, ab2, out);
}

// Round 16
// 213.549 us; speedup vs baseline: 2.6049x; 2.6049x over previous
//
#include <hip/hip_runtime.h>
#include <hip/hip_bf16.h>

#define B_ 4
#define N_ 512
#define D_ 128
#define LOG2E 1.4426950408889634f

typedef __attribute__((ext_vector_type(8))) short bf16x8;
typedef __attribute__((ext_vector_type(4))) short s16x4;
typedef __attribute__((ext_vector_type(4))) float f32x4;
typedef __attribute__((ext_vector_type(16))) float f32x16;

__device__ __forceinline__ f32x4 mfma16(bf16x8 a, bf16x8 b, f32x4 c) {
    return __builtin_amdgcn_mfma_f32_16x16x32_bf16(a, b, c, 0, 0, 0);
}
__device__ __forceinline__ f32x16 mfma32(bf16x8 a, bf16x8 b, f32x16 c) {
    return __builtin_amdgcn_mfma_f32_32x32x16_bf16(a, b, c, 0, 0, 0);
}
__device__ __forceinline__ short bf16b(float x) {
    __hip_bfloat16 h = __float2bfloat16(x);
    return *reinterpret_cast<short*>(&h);
}
__device__ __forceinline__ float b2f(short s) {
    unsigned u = ((unsigned)(unsigned short)s) << 16;
    union { unsigned u; float f; } c; c.u = u; return c.f;
}

// ---------------- prep 1: weight folds only (small) ----------------
// aW2T[d][k]=aW2[k][d]*LOG2E; pW2T[d][h]=pW2[h][d]; W12T[n][h]=(pW2@aW1)^T
// Wqa[d][n]=Wq@aW1, Wka[d][n]=Wk@aW1  (so qa/ka come straight from x)
// cvec2[n]=ab1[n]+sum_j(pb2[j]+bq[j]-bk[j])*aW1[j][n]
__global__ void prep_weights_kernel(const float* __restrict__ aW1, const float* __restrict__ aW2,
                                    const float* __restrict__ pW2, const float* __restrict__ pb2,
                                    const float* __restrict__ ab1, const float* __restrict__ Wqkv,
                                    const float* __restrict__ bqkv,
                                    __hip_bfloat16* __restrict__ aW2T, __hip_bfloat16* __restrict__ pW2T,
                                    __hip_bfloat16* __restrict__ W12T, float* __restrict__ cvec,
                                    float* __restrict__ Wqa, float* __restrict__ Wka) {
    int idx = blockIdx.x * 256 + threadIdx.x;   // 128 blocks -> 32768
    {
        int n = idx >> 8, k2 = idx & 255;
        aW2T[idx] = __float2bfloat16(aW2[k2 * 128 + n] * LOG2E);
    }
    if (idx < 128 * 64) {
        int n = idx >> 6, k2 = idx & 63;
        pW2T[idx] = __float2bfloat16(pW2[k2 * 128 + n]);
    }
    if (idx < 256 * 64) {
        int n = idx >> 6, h = idx & 63;
        float s = 0.f;
#pragma unroll 8
        for (int d = 0; d < 128; ++d) s += pW2[h * 128 + d] * aW1[d * 256 + n];
        W12T[idx] = __float2bfloat16(s);
    }
    {
        int d = idx >> 8, n2 = idx & 255;
        float sq = 0.f, sk = 0.f;
#pragma unroll 4
        for (int j = 0; j < 128; ++j) {
            float a = aW1[j * 256 + n2];
            sq = fmaf(Wqkv[d * 384 + j], a, sq);
            sk = fmaf(Wqkv[d * 384 + 128 + j], a, sk);
        }
        Wqa[idx] = sq;
        Wka[idx] = sk;
    }
    if (idx < 256) {
        float s = ab1[idx];
#pragma unroll 4
        for (int j = 0; j < 128; ++j)
            s = fmaf(pb2[j] + bqkv[j] - bqkv[128 + j], aW1[j * 256 + idx], s);
        cvec[idx] = s;
    }
}

// ---------------- prep 2: qa/kab_t/vb_t straight from x, + posw ----------------
// blocks [0,320): token-GEMM (16 tokens/thread, 640 output cols)
// blocks [320,448): posw
__global__ void prep_x_kernel(const float* __restrict__ x, const float* __restrict__ Wqkv,
                              const float* __restrict__ bqkv, const float* __restrict__ pb2,
                              const float* __restrict__ Wqa, const float* __restrict__ Wka,
                              const float* __restrict__ pos, const float* __restrict__ pW1,
                              float* __restrict__ qa, short* __restrict__ kab_t,
                              short* __restrict__ vb_t, float* __restrict__ posw) {
    const int bid = blockIdx.x;
    const int tid = threadIdx.x;
    if (bid < 320) {
        int idx = bid * 256 + tid;          // 0..81919 = 128 groups * 640 cols
        int m = idx % 640;
        int g = idx / 640;
        int bn0 = g * 16;
        int b = bn0 >> 9, n0 = bn0 & (N_ - 1);
        const float* xp = x + (b * D_) * N_ + n0;
        float acc[16];
#pragma unroll
        for (int t = 0; t < 16; ++t) acc[t] = 0.f;
#pragma unroll 2
        for (int d = 0; d < D_; ++d) {
            float wv = (m < 256) ? Wqa[d * 256 + m]
                     : (m < 512) ? Wka[d * 256 + (m - 256)]
                                 : Wqkv[d * 384 + 256 + (m - 512)];
            const float* xr = xp + d * N_;
            float4 x0 = *(const float4*)(xr);
            float4 x1 = *(const float4*)(xr + 4);
            float4 x2 = *(const float4*)(xr + 8);
            float4 x3 = *(const float4*)(xr + 12);
            acc[0]  = fmaf(x0.x, wv, acc[0]);  acc[1]  = fmaf(x0.y, wv, acc[1]);
            acc[2]  = fmaf(x0.z, wv, acc[2]);  acc[3]  = fmaf(x0.w, wv, acc[3]);
            acc[4]  = fmaf(x1.x, wv, acc[4]);  acc[5]  = fmaf(x1.y, wv, acc[5]);
            acc[6]  = fmaf(x1.z, wv, acc[6]);  acc[7]  = fmaf(x1.w, wv, acc[7]);
            acc[8]  = fmaf(x2.x, wv, acc[8]);  acc[9]  = fmaf(x2.y, wv, acc[9]);
            acc[10] = fmaf(x2.z, wv, acc[10]); acc[11] = fmaf(x2.w, wv, acc[11]);
            acc[12] = fmaf(x3.x, wv, acc[12]); acc[13] = fmaf(x3.y, wv, acc[13]);
            acc[14] = fmaf(x3.z, wv, acc[14]); acc[15] = fmaf(x3.w, wv, acc[15]);
        }
        if (m < 256) {
            // qa (bias folded into cvec2)
#pragma unroll
            for (int t = 0; t < 16; ++t)
                qa[(size_t)(bn0 + t) * 256 + m] = acc[t];
        } else if (m < 512) {
            // kab_t tiled bf16 (no bias; folded into cvec2 with minus sign)
            int col = m - 256;
            int jt = n0 >> 6;
            int mt = (n0 >> 4) & 3;
            int w = col >> 5, nt = (col >> 4) & 1, lc = col & 15;
            size_t base = (((((size_t)b * 8 + jt) * 8 + w) * 2 + nt) * 4 + mt) * 256;
#pragma unroll
            for (int lg = 0; lg < 4; ++lg) {
                s16x4 pk;
                pk[0] = bf16b(acc[lg * 4 + 0]); pk[1] = bf16b(acc[lg * 4 + 1]);
                pk[2] = bf16b(acc[lg * 4 + 2]); pk[3] = bf16b(acc[lg * 4 + 3]);
                *(s16x4*)(kab_t + base + (size_t)(lg * 16 + lc) * 4) = pk;
            }
        } else {
            // vb_t tiled bf16, bias bv + pb2 folded in
            int d = m - 512;
            float bias = bqkv[256 + d] + pb2[d];
            int jt = n0 >> 6;
            int jr = n0 & 63;
            int rtv = jr >> 5;
            int jrr0 = jr & 31;
            int ct = d >> 5;
            int lbase = d & 31;
            size_t tilebase = (size_t)b * 65536 + (size_t)jt * 8192
                            + (size_t)((rtv * 4 + ct) * 64) * 16;
#pragma unroll
            for (int tt = 0; tt < 4; ++tt) {
                int jrr = jrr0 + tt * 4;
                int rb = 4 * (jrr >> 3);
                int hi = (jrr >> 2) & 1;
                s16x4 pk;
                pk[0] = bf16b(acc[tt * 4 + 0] + bias); pk[1] = bf16b(acc[tt * 4 + 1] + bias);
                pk[2] = bf16b(acc[tt * 4 + 2] + bias); pk[3] = bf16b(acc[tt * 4 + 3] + bias);
                *(s16x4*)(vb_t + tilebase + (size_t)(lbase + 32 * hi) * 16 + rb) = pk;
            }
        }
    } else {
        int i4 = (bid - 320) * 256 + tid;      // 0..32767
        int t = i4 >> 4, h4 = (i4 & 15) * 4;
        float p0 = pos[t * 3 + 0], p1 = pos[t * 3 + 1], p2 = pos[t * 3 + 2];
#pragma unroll
        for (int e = 0; e < 4; ++e) {
            int h = h4 + e;
            posw[t * 64 + h] = p0 * pW1[h] + p1 * pW1[64 + h] + p2 * pW1[128 + h];
        }
    }
}

// ---------------- main fused kernel: R13 structure + MFMA C-input folds ----------------
__global__ __launch_bounds__(512, 2) void fused_attn_kernel(
    const float* __restrict__ qa, const short* __restrict__ kab_t,
    const short* __restrict__ vb_t,
    const float* __restrict__ posw, const float* __restrict__ pb1,
    const __hip_bfloat16* __restrict__ pW2T,
    const __hip_bfloat16* __restrict__ W12T, const float* __restrict__ cvec,
    const __hip_bfloat16* __restrict__ aW2T,
    float* __restrict__ out)
{
    __shared__ __hip_bfloat16 ph_s[2][64][72];
    __shared__ __hip_bfloat16 hid_s[2][64][264];
    __shared__ float pwi_s[2][64];
    __shared__ float mrg_s[2][4][32][2];

    const int tid = threadIdx.x;
    const int w   = tid >> 6;
    const int l   = tid & 63;
    const int lg  = l >> 4;
    const int lc  = l & 15;
    const int l31 = l & 31;
    const int hi  = l >> 5;
    const int rt  = w >> 2;
    const int ct  = w & 3;
    const int gx8 = ((l31 >> 2) & 3) << 3;

    const int blk = (blockIdx.x & 7) * 128 + (blockIdx.x >> 3);
    const int b   = blk >> 8;
    const int i0  = (blk & 255) * 2;

    if (tid < 128) {
        int ii = tid >> 6, h = tid & 63;
        pwi_s[ii][h] = posw[(size_t)(b * N_ + i0 + ii) * 64 + h] + pb1[h];
    }

    const int col0  = 32 * w + lc;
    const int dcol2 = 32 * ct + l31;

    const float qr00 = qa[(b * N_ + i0) * 256 + col0] + cvec[col0];
    const float qr01 = qa[(b * N_ + i0) * 256 + col0 + 16] + cvec[col0 + 16];
    const float qr10 = qa[(b * N_ + i0 + 1) * 256 + col0] + cvec[col0];
    const float qr11 = qa[(b * N_ + i0 + 1) * 256 + col0 + 16] + cvec[col0 + 16];

    const __hip_bfloat16* a2base = aW2T + (size_t)dcol2 * 256 + 8 * hi;
    bf16x8 bw2[16];
#pragma unroll
    for (int ks = 0; ks < 16; ++ks)
        bw2[ks] = *(const bf16x8*)(a2base + 16 * ks);
    const __hip_bfloat16* ppb = pW2T + (size_t)dcol2 * 64 + 8 * hi;
    const __hip_bfloat16* p12b = W12T + (size_t)(32 * w + lc) * 64 + 8 * lg;

    float l_run[2] = {0.f, 0.f};
    float o_run[2] = {0.f, 0.f};
    float vv[2][16];

    const short* ktp0 = kab_t + (size_t)b * 131072 + w * 2048 + l * 4;
    const short* vtp0 = vb_t + (size_t)b * 65536 + ((rt * 4 + ct) * 64 + l) * 16;

    const int jl = tid >> 3;
    const int hb = (tid & 7) * 8;

    s16x4 vb4[4], kv[2][4];
#pragma unroll
    for (int q4 = 0; q4 < 4; ++q4)
        vb4[q4] = *(const s16x4*)(vtp0 + 4 * q4);
#pragma unroll
    for (int nt = 0; nt < 2; ++nt)
#pragma unroll
        for (int mt = 0; mt < 4; ++mt)
            kv[nt][mt] = *(const s16x4*)(ktp0 + nt * 1024 + mt * 256);
    __syncthreads();

    for (int jt = 0; jt < 8; ++jt) {
        bf16x8 bwp[4], bw12[2][2];
#pragma unroll
        for (int ks = 0; ks < 4; ++ks)
            bwp[ks] = *(const bf16x8*)(ppb + 16 * ks);
#pragma unroll
        for (int nt = 0; nt < 2; ++nt)
#pragma unroll
            for (int k2 = 0; k2 < 2; ++k2)
                bw12[nt][k2] = *(const bf16x8*)(p12b + nt * 1024 + k2 * 32);

        // ---- A: ph[ii][64][64] = relu(pwi[ii] - posw_j) ----
        {
            const float* pj = posw + (size_t)(b * N_ + jt * 64 + jl) * 64 + hb;
            float4 x0 = *(const float4*)pj;
            float4 x1 = *(const float4*)(pj + 4);
            float xr[8] = {x0.x, x0.y, x0.z, x0.w, x1.x, x1.y, x1.z, x1.w};
#pragma unroll
            for (int ii = 0; ii < 2; ++ii) {
                bf16x8 tv;
#pragma unroll
                for (int h = 0; h < 8; ++h)
                    tv[h] = bf16b(fmaxf(pwi_s[ii][hb + h] - xr[h], 0.f));
                *(bf16x8*)(&ph_s[ii][jl][hb]) = tv;
            }
        }
        __syncthreads();

        // ================= R1: rpe + GEMM1 (MFMA C-input folds) =================
#pragma unroll
        for (int ii = 0; ii < 2; ++ii) {
            f32x16 accr;
#pragma unroll
            for (int r = 0; r < 16; ++r)
                accr[r] = b2f(vb4[r >> 2][r & 3]);       // C-init = v (+pb2 folded)
#pragma unroll
            for (int ks = 0; ks < 4; ++ks) {
                bf16x8 a = *(const bf16x8*)(&ph_s[ii][32 * rt + l31][16 * ks + 8 * hi]);
                accr = mfma32(a, bwp[ks], accr);
            }
#pragma unroll
            for (int r = 0; r < 16; ++r)
                vv[ii][r] = accr[r];
        }
#pragma unroll
        for (int ii = 0; ii < 2; ++ii) {
#pragma unroll
            for (int mt = 0; mt < 4; ++mt) {
                bf16x8 a0 = *(const bf16x8*)(&ph_s[ii][mt * 16 + lc][8 * lg]);
                bf16x8 a1 = *(const bf16x8*)(&ph_s[ii][mt * 16 + lc][32 + 8 * lg]);
#pragma unroll
                for (int nt = 0; nt < 2; ++nt) {
                    const float qv = ii ? (nt ? qr11 : qr10) : (nt ? qr01 : qr00);
                    f32x4 acc;
#pragma unroll
                    for (int r = 0; r < 4; ++r)
                        acc[r] = qv - b2f(kv[nt][mt][r]); // C-init = q - k
                    acc = mfma16(a0, bw12[nt][0], acc);
                    acc = mfma16(a1, bw12[nt][1], acc);
                    const int colw = 32 * w + (((16 * nt + lc) ^ (8 * lg)) & 31);
#pragma unroll
                    for (int r = 0; r < 4; ++r) {
                        int row = mt * 16 + 4 * lg + r;
                        hid_s[ii][row][colw] = __float2bfloat16(fmaxf(acc[r], 0.f));
                    }
                }
            }
        }
        __syncthreads();

        // ====== R2: prefetch(jt+1) into dead regs, then GEMM2 + max-free softmax ======
        {
            const int jtn = (jt < 7) ? jt + 1 : 7;
            const short* vtp = vtp0 + (size_t)jtn * 8192;
            const short* ktp = ktp0 + (size_t)jtn * 16384;
#pragma unroll
            for (int q4 = 0; q4 < 4; ++q4)
                vb4[q4] = *(const s16x4*)(vtp + 4 * q4);
#pragma unroll
            for (int nt = 0; nt < 2; ++nt)
#pragma unroll
                for (int mt = 0; mt < 4; ++mt)
                    kv[nt][mt] = *(const s16x4*)(ktp + nt * 1024 + mt * 256);
        }

#pragma unroll
        for (int ii = 0; ii < 2; ++ii) {
            f32x16 acc2a = {0.f,0.f,0.f,0.f,0.f,0.f,0.f,0.f,0.f,0.f,0.f,0.f,0.f,0.f,0.f,0.f};
            f32x16 acc2b = {0.f,0.f,0.f,0.f,0.f,0.f,0.f,0.f,0.f,0.f,0.f,0.f,0.f,0.f,0.f,0.f};
            const short* hrow = (const short*)&hid_s[ii][32 * rt + l31][0];
#pragma unroll
            for (int ks = 0; ks < 8; ++ks) {
                bf16x8 aa = *(const bf16x8*)(hrow + ((16 * ks + 8 * hi) ^ gx8));
                bf16x8 ab = *(const bf16x8*)(hrow + ((16 * (ks + 8) + 8 * hi) ^ gx8));
                acc2a = mfma32(aa, bw2[ks], acc2a);
                acc2b = mfma32(ab, bw2[ks + 8], acc2b);
            }
            float lp[4] = {0.f, 0.f, 0.f, 0.f};
            float op[4] = {0.f, 0.f, 0.f, 0.f};
#pragma unroll
            for (int r = 0; r < 16; ++r) {
                float e = __builtin_amdgcn_exp2f(acc2a[r] + acc2b[r]);
                lp[r & 3] += e;
                op[r & 3] = fmaf(e, vv[ii][r], op[r & 3]);
            }
            l_run[ii] += (lp[0] + lp[1]) + (lp[2] + lp[3]);
            o_run[ii] += (op[0] + op[1]) + (op[2] + op[3]);
        }
    }

    // ---- final merge: pure sums ----
    float L1[2], O1[2];
#pragma unroll
    for (int ii = 0; ii < 2; ++ii) {
        L1[ii] = l_run[ii] + __shfl_xor(l_run[ii], 32);
        O1[ii] = o_run[ii] + __shfl_xor(o_run[ii], 32);
        if (rt == 1 && hi == 0) {
            mrg_s[ii][ct][l31][0] = L1[ii];
            mrg_s[ii][ct][l31][1] = O1[ii];
        }
    }
    __syncthreads();
    if (rt == 0 && hi == 0) {
#pragma unroll
        for (int ii = 0; ii < 2; ++ii) {
            float L = L1[ii] + mrg_s[ii][ct][l31][0];
            float O = O1[ii] + mrg_s[ii][ct][l31][1];
            out[((size_t)b * D_ + dcol2) * N_ + i0 + ii] = O / L;
        }
    }
}

extern "C" void kernel_launch(void* const* d_in, const int* in_sizes, int n_in,
                              void* d_out, int out_size, void* d_ws, size_t ws_size,
                              hipStream_t stream) {
    const float* x    = (const float*)d_in[0];
    const float* pos  = (const float*)d_in[1];
    const float* Wqkv = (const float*)d_in[2];
    const float* bqkv = (const float*)d_in[3];
    const float* pW1  = (const float*)d_in[4];
    const float* pb1  = (const float*)d_in[5];
    const float* pW2  = (const float*)d_in[6];
    const float* pb2  = (const float*)d_in[7];
    const float* aW1  = (const float*)d_in[8];
    const float* ab1  = (const float*)d_in[9];
    const float* aW2  = (const float*)d_in[10];
    const float* ab2  = (const float*)d_in[11];
    float* out = (float*)d_out;

    float* qa   = (float*)d_ws;            // 524288 f32
    float* posw = qa + B_ * N_ * 256;      // 131072 f32
    float* cvec = posw + B_ * N_ * 64;     // 256 f32
    float* Wqa  = cvec + 256;              // 32768 f32
    float* Wka  = Wqa + 32768;             // 32768 f32
    short* kab_t = (short*)(Wka + 32768);  // 524288 bf16 (16x16-tiled)
    short* vb_t  = kab_t + B_ * N_ * 256;  // 262144 bf16 (32x32-tiled, +pb2+bv)
    __hip_bfloat16* aW2T = (__hip_bfloat16*)(vb_t + B_ * N_ * D_);  // 32768
    __hip_bfloat16* pW2T = aW2T + 128 * 256;                        // 8192
    __hip_bfloat16* W12T = pW2T + 128 * 64;                         // 16384

    hipLaunchKernelGGL(prep_weights_kernel, dim3(128), dim3(256), 0, stream,
                       aW1, aW2, pW2, pb2, ab1, Wqkv, bqkv,
                       aW2T, pW2T, W12T, cvec, Wqa, Wka);
    hipLaunchKernelGGL(prep_x_kernel, dim3(448), dim3(256), 0, stream,
                       x, Wqkv, bqkv, pb2, Wqa, Wka, pos, pW1,
                       qa, kab_t, vb_t, posw);
    hipLaunchKernelGGL(fused_attn_kernel, dim3(1024), dim3(512), 0, stream,
                       qa, kab_t, vb_t, posw, pb1, pW2T, W12T, cvec, aW2T, out);
}

// Round 17
// 211.576 us; speedup vs baseline: 2.6292x; 1.0093x over previous
//
#include <hip/hip_runtime.h>
#include <hip/hip_bf16.h>

#define B_ 4
#define N_ 512
#define D_ 128
#define LOG2E 1.4426950408889634f

typedef __attribute__((ext_vector_type(8))) short bf16x8;
typedef __attribute__((ext_vector_type(4))) short s16x4;
typedef __attribute__((ext_vector_type(4))) float f32x4;
typedef __attribute__((ext_vector_type(16))) float f32x16;

__device__ __forceinline__ f32x4 mfma16(bf16x8 a, bf16x8 b, f32x4 c) {
    return __builtin_amdgcn_mfma_f32_16x16x32_bf16(a, b, c, 0, 0, 0);
}
__device__ __forceinline__ f32x16 mfma32(bf16x8 a, bf16x8 b, f32x16 c) {
    return __builtin_amdgcn_mfma_f32_32x32x16_bf16(a, b, c, 0, 0, 0);
}
__device__ __forceinline__ short bf16b(float x) {
    __hip_bfloat16 h = __float2bfloat16(x);
    return *reinterpret_cast<short*>(&h);
}
__device__ __forceinline__ float b2f(short s) {
    unsigned u = ((unsigned)(unsigned short)s) << 16;
    union { unsigned u; float f; } c; c.u = u; return c.f;
}

// ---------------- prep A (merged): weights fold + posw + qkv (R13 structure) ----------------
__global__ void prep_misc_kernel(const float* __restrict__ aW1, const float* __restrict__ aW2,
                                 const float* __restrict__ pW2, const float* __restrict__ pb2,
                                 const float* __restrict__ ab1, const float* __restrict__ pos,
                                 const float* __restrict__ pW1, const float* __restrict__ x,
                                 const float* __restrict__ Wqkv, const float* __restrict__ bqkv,
                                 __hip_bfloat16* __restrict__ aW2T, __hip_bfloat16* __restrict__ pW2T,
                                 __hip_bfloat16* __restrict__ W12T, float* __restrict__ cvec,
                                 float* __restrict__ posw,
                                 float* __restrict__ q, float* __restrict__ k,
                                 short* __restrict__ vb_t) {
    const int bid = blockIdx.x;
    const int tid = threadIdx.x;
    if (bid < 128) {
        int idx = bid * 256 + tid;
        {
            int n = idx >> 8, k2 = idx & 255;
            aW2T[idx] = __float2bfloat16(aW2[k2 * 128 + n] * LOG2E);
        }
        if (idx < 128 * 64) {
            int n = idx >> 6, k2 = idx & 63;
            pW2T[idx] = __float2bfloat16(pW2[k2 * 128 + n]);
        }
        if (idx < 256 * 64) {
            int n = idx >> 6, h = idx & 63;
            float s = 0.f;
#pragma unroll 8
            for (int d = 0; d < 128; ++d) s += pW2[h * 128 + d] * aW1[d * 256 + n];
            W12T[idx] = __float2bfloat16(s);
        }
        if (idx < 256) {
            float s = ab1[idx];
#pragma unroll 8
            for (int d = 0; d < 128; ++d) s += pb2[d] * aW1[d * 256 + idx];
            cvec[idx] = s;
        }
    } else if (bid < 256) {
        int i4 = (bid - 128) * 256 + tid;
        int t = i4 >> 4, h4 = (i4 & 15) * 4;
        float p0 = pos[t * 3 + 0], p1 = pos[t * 3 + 1], p2 = pos[t * 3 + 2];
#pragma unroll
        for (int e = 0; e < 4; ++e) {
            int h = h4 + e;
            posw[t * 64 + h] = p0 * pW1[h] + p1 * pW1[64 + h] + p2 * pW1[128 + h];
        }
    } else {
        int idx = (bid - 256) * 256 + tid;
        int m = idx % 384;
        int g = idx / 384;
        int bn0 = g * 16;
        int b = bn0 >> 9, n0 = bn0 & (N_ - 1);
        const float* xp = x + (b * D_) * N_ + n0;
        float bias = bqkv[m];
        float acc[16];
#pragma unroll
        for (int t = 0; t < 16; ++t) acc[t] = bias;
#pragma unroll 2
        for (int d = 0; d < D_; ++d) {
            float wv = Wqkv[d * 384 + m];
            const float* xr = xp + d * N_;
            float4 x0 = *(const float4*)(xr);
            float4 x1 = *(const float4*)(xr + 4);
            float4 x2 = *(const float4*)(xr + 8);
            float4 x3 = *(const float4*)(xr + 12);
            acc[0]  = fmaf(x0.x, wv, acc[0]);  acc[1]  = fmaf(x0.y, wv, acc[1]);
            acc[2]  = fmaf(x0.z, wv, acc[2]);  acc[3]  = fmaf(x0.w, wv, acc[3]);
            acc[4]  = fmaf(x1.x, wv, acc[4]);  acc[5]  = fmaf(x1.y, wv, acc[5]);
            acc[6]  = fmaf(x1.z, wv, acc[6]);  acc[7]  = fmaf(x1.w, wv, acc[7]);
            acc[8]  = fmaf(x2.x, wv, acc[8]);  acc[9]  = fmaf(x2.y, wv, acc[9]);
            acc[10] = fmaf(x2.z, wv, acc[10]); acc[11] = fmaf(x2.w, wv, acc[11]);
            acc[12] = fmaf(x3.x, wv, acc[12]); acc[13] = fmaf(x3.y, wv, acc[13]);
            acc[14] = fmaf(x3.z, wv, acc[14]); acc[15] = fmaf(x3.w, wv, acc[15]);
        }
        if (m < 256) {
            float* dst = (m < 128) ? q : k;
            int mm = m & 127;
#pragma unroll
            for (int t = 0; t < 16; ++t)
                dst[(bn0 + t) * D_ + mm] = acc[t];
        } else {
            int d = m & 127;
            float pv = pb2[d];
            int jt = n0 >> 6;
            int jr = n0 & 63;
            int rtv = jr >> 5;
            int jrr0 = jr & 31;
            int ct = d >> 5;
            int lbase = d & 31;
            size_t tilebase = (size_t)b * 65536 + (size_t)jt * 8192
                            + (size_t)((rtv * 4 + ct) * 64) * 16;
#pragma unroll
            for (int tt = 0; tt < 4; ++tt) {
                int jrr = jrr0 + tt * 4;
                int rb = 4 * (jrr >> 3);
                int hi = (jrr >> 2) & 1;
                s16x4 pk;
                pk[0] = bf16b(acc[tt * 4 + 0] + pv); pk[1] = bf16b(acc[tt * 4 + 1] + pv);
                pk[2] = bf16b(acc[tt * 4 + 2] + pv); pk[3] = bf16b(acc[tt * 4 + 3] + pv);
                *(s16x4*)(vb_t + tilebase + (size_t)(lbase + 32 * hi) * 16 + rb) = pk;
            }
        }
    }
}

// ---------------- prep B: qa = q@aW1 (fp32), ka = k@aW1 -> 16x16-tiled bf16 ----------------
__global__ void qka_kernel(const float* __restrict__ q, const float* __restrict__ k,
                           const float* __restrict__ aW1,
                           float* __restrict__ qa, short* __restrict__ kab_t) {
    int col = threadIdx.x;
    int bn0 = blockIdx.x * 8;
    int b = bn0 >> 9, n0 = bn0 & (N_ - 1);
    const float* qp = q + (size_t)bn0 * D_;
    const float* kp = k + (size_t)bn0 * D_;
    float aq[8], ak[8];
#pragma unroll
    for (int t = 0; t < 8; ++t) { aq[t] = 0.f; ak[t] = 0.f; }
#pragma unroll 2
    for (int d = 0; d < D_; ++d) {
        float wv = aW1[d * 256 + col];
#pragma unroll
        for (int t = 0; t < 8; ++t) {
            aq[t] = fmaf(qp[t * D_ + d], wv, aq[t]);
            ak[t] = fmaf(kp[t * D_ + d], wv, ak[t]);
        }
    }
#pragma unroll
    for (int t = 0; t < 8; ++t)
        qa[(size_t)(bn0 + t) * 256 + col] = aq[t];
    int jt = n0 >> 6;
    int mt = (n0 >> 4) & 3;
    int lg0 = (n0 >> 2) & 3;
    int w = col >> 5, nt = (col >> 4) & 1, lc = col & 15;
#pragma unroll
    for (int half = 0; half < 2; ++half) {
        int lg = lg0 + half;
        int l = lg * 16 + lc;
        s16x4 pk;
        pk[0] = bf16b(ak[half * 4 + 0]); pk[1] = bf16b(ak[half * 4 + 1]);
        pk[2] = bf16b(ak[half * 4 + 2]); pk[3] = bf16b(ak[half * 4 + 3]);
        size_t base = (((((size_t)b * 8 + jt) * 8 + w) * 2 + nt) * 4 + mt) * 256 + l * 4;
        *(s16x4*)(kab_t + base) = pk;
    }
}

// -------- main fused kernel: R13 structure + C-init folds + pwi-in-registers --------
__global__ __launch_bounds__(512, 2) void fused_attn_kernel(
    const float* __restrict__ qa, const short* __restrict__ kab_t,
    const short* __restrict__ vb_t,
    const float* __restrict__ posw, const float* __restrict__ pb1,
    const __hip_bfloat16* __restrict__ pW2T,
    const __hip_bfloat16* __restrict__ W12T, const float* __restrict__ cvec,
    const __hip_bfloat16* __restrict__ aW2T,
    float* __restrict__ out)
{
    __shared__ __hip_bfloat16 ph_s[2][64][72];
    __shared__ __hip_bfloat16 hid_s[2][64][264];
    __shared__ float mrg_s[2][4][32][2];

    const int tid = threadIdx.x;
    const int w   = tid >> 6;
    const int l   = tid & 63;
    const int lg  = l >> 4;
    const int lc  = l & 15;
    const int l31 = l & 31;
    const int hi  = l >> 5;
    const int rt  = w >> 2;
    const int ct  = w & 3;
    const int gx8 = ((l31 >> 2) & 3) << 3;

    const int blk = (blockIdx.x & 7) * 128 + (blockIdx.x >> 3);
    const int b   = blk >> 8;
    const int i0  = (blk & 255) * 2;

    const int col0  = 32 * w + lc;
    const int dcol2 = 32 * ct + l31;

    const float qr00 = qa[(b * N_ + i0) * 256 + col0] + cvec[col0];
    const float qr01 = qa[(b * N_ + i0) * 256 + col0 + 16] + cvec[col0 + 16];
    const float qr10 = qa[(b * N_ + i0 + 1) * 256 + col0] + cvec[col0];
    const float qr11 = qa[(b * N_ + i0 + 1) * 256 + col0 + 16] + cvec[col0 + 16];

    const __hip_bfloat16* a2base = aW2T + (size_t)dcol2 * 256 + 8 * hi;
    bf16x8 bw2[16];
#pragma unroll
    for (int ks = 0; ks < 16; ++ks)
        bw2[ks] = *(const bf16x8*)(a2base + 16 * ks);
    const __hip_bfloat16* ppb = pW2T + (size_t)dcol2 * 64 + 8 * hi;
    const __hip_bfloat16* p12b = W12T + (size_t)(32 * w + lc) * 64 + 8 * lg;

    float l_run[2] = {0.f, 0.f};
    float o_run[2] = {0.f, 0.f};
    float vv[2][16];

    const short* ktp0 = kab_t + (size_t)b * 131072 + w * 2048 + l * 4;
    const short* vtp0 = vb_t + (size_t)b * 65536 + ((rt * 4 + ct) * 64 + l) * 16;

    const int jl = tid >> 3;
    const int hb = (tid & 7) * 8;

    // ---- pwi in registers: this thread's 2x8 slice of posw_i + pb1 ----
    float pwi_r[2][8];
    {
        float4 pba = *(const float4*)(pb1 + hb);
        float4 pbb = *(const float4*)(pb1 + hb + 4);
#pragma unroll
        for (int ii = 0; ii < 2; ++ii) {
            const float* pw = posw + (size_t)(b * N_ + i0 + ii) * 64 + hb;
            float4 a0 = *(const float4*)pw;
            float4 a1 = *(const float4*)(pw + 4);
            pwi_r[ii][0] = a0.x + pba.x; pwi_r[ii][1] = a0.y + pba.y;
            pwi_r[ii][2] = a0.z + pba.z; pwi_r[ii][3] = a0.w + pba.w;
            pwi_r[ii][4] = a1.x + pbb.x; pwi_r[ii][5] = a1.y + pbb.y;
            pwi_r[ii][6] = a1.z + pbb.z; pwi_r[ii][7] = a1.w + pbb.w;
        }
    }

    // ---- prologue: kv/vb loads for jt=0 ----
    s16x4 vb4[4], kv[2][4];
#pragma unroll
    for (int q4 = 0; q4 < 4; ++q4)
        vb4[q4] = *(const s16x4*)(vtp0 + 4 * q4);
#pragma unroll
    for (int nt = 0; nt < 2; ++nt)
#pragma unroll
        for (int mt = 0; mt < 4; ++mt)
            kv[nt][mt] = *(const s16x4*)(ktp0 + nt * 1024 + mt * 256);

    for (int jt = 0; jt < 8; ++jt) {
        // ---- per-jt weight reloads (jt-invariant addresses, L2-hot) ----
        bf16x8 bwp[4], bw12[2][2];
#pragma unroll
        for (int ks = 0; ks < 4; ++ks)
            bwp[ks] = *(const bf16x8*)(ppb + 16 * ks);
#pragma unroll
        for (int nt = 0; nt < 2; ++nt)
#pragma unroll
            for (int k2 = 0; k2 < 2; ++k2)
                bw12[nt][k2] = *(const bf16x8*)(p12b + nt * 1024 + k2 * 32);

        // ---- A: ph[ii][64][64] = relu(pwi_r[ii] - posw_j) ----
        {
            const float* pj = posw + (size_t)(b * N_ + jt * 64 + jl) * 64 + hb;
            float4 x0 = *(const float4*)pj;
            float4 x1 = *(const float4*)(pj + 4);
            float xr[8] = {x0.x, x0.y, x0.z, x0.w, x1.x, x1.y, x1.z, x1.w};
#pragma unroll
            for (int ii = 0; ii < 2; ++ii) {
                bf16x8 tv;
#pragma unroll
                for (int h = 0; h < 8; ++h)
                    tv[h] = bf16b(fmaxf(pwi_r[ii][h] - xr[h], 0.f));
                *(bf16x8*)(&ph_s[ii][jl][hb]) = tv;
            }
        }
        __syncthreads();

        // ================= R1: rpe + GEMM1 (MFMA C-input folds) =================
#pragma unroll
        for (int ii = 0; ii < 2; ++ii) {
            f32x16 accr;
#pragma unroll
            for (int r = 0; r < 16; ++r)
                accr[r] = b2f(vb4[r >> 2][r & 3]);       // C-init = v (+pb2 folded)
#pragma unroll
            for (int ks = 0; ks < 4; ++ks) {
                bf16x8 a = *(const bf16x8*)(&ph_s[ii][32 * rt + l31][16 * ks + 8 * hi]);
                accr = mfma32(a, bwp[ks], accr);
            }
#pragma unroll
            for (int r = 0; r < 16; ++r)
                vv[ii][r] = accr[r];
        }
#pragma unroll
        for (int ii = 0; ii < 2; ++ii) {
#pragma unroll
            for (int mt = 0; mt < 4; ++mt) {
                bf16x8 a0 = *(const bf16x8*)(&ph_s[ii][mt * 16 + lc][8 * lg]);
                bf16x8 a1 = *(const bf16x8*)(&ph_s[ii][mt * 16 + lc][32 + 8 * lg]);
#pragma unroll
                for (int nt = 0; nt < 2; ++nt) {
                    const float qv = ii ? (nt ? qr11 : qr10) : (nt ? qr01 : qr00);
                    f32x4 acc;
#pragma unroll
                    for (int r = 0; r < 4; ++r)
                        acc[r] = qv - b2f(kv[nt][mt][r]); // C-init = q - k
                    acc = mfma16(a0, bw12[nt][0], acc);
                    acc = mfma16(a1, bw12[nt][1], acc);
                    const int colw = 32 * w + (((16 * nt + lc) ^ (8 * lg)) & 31);
#pragma unroll
                    for (int r = 0; r < 4; ++r) {
                        int row = mt * 16 + 4 * lg + r;
                        hid_s[ii][row][colw] = __float2bfloat16(fmaxf(acc[r], 0.f));
                    }
                }
            }
        }
        __syncthreads();

        // ====== R2: prefetch(jt+1) into dead regs, then GEMM2 + max-free softmax ======
        {
            const int jtn = (jt < 7) ? jt + 1 : 7;
            const short* vtp = vtp0 + (size_t)jtn * 8192;
            const short* ktp = ktp0 + (size_t)jtn * 16384;
#pragma unroll
            for (int q4 = 0; q4 < 4; ++q4)
                vb4[q4] = *(const s16x4*)(vtp + 4 * q4);
#pragma unroll
            for (int nt = 0; nt < 2; ++nt)
#pragma unroll
                for (int mt = 0; mt < 4; ++mt)
                    kv[nt][mt] = *(const s16x4*)(ktp + nt * 1024 + mt * 256);
        }

#pragma unroll
        for (int ii = 0; ii < 2; ++ii) {
            f32x16 acc2a = {0.f,0.f,0.f,0.f,0.f,0.f,0.f,0.f,0.f,0.f,0.f,0.f,0.f,0.f,0.f,0.f};
            f32x16 acc2b = {0.f,0.f,0.f,0.f,0.f,0.f,0.f,0.f,0.f,0.f,0.f,0.f,0.f,0.f,0.f,0.f};
            const short* hrow = (const short*)&hid_s[ii][32 * rt + l31][0];
#pragma unroll
            for (int ks = 0; ks < 8; ++ks) {
                bf16x8 aa = *(const bf16x8*)(hrow + ((16 * ks + 8 * hi) ^ gx8));
                bf16x8 ab = *(const bf16x8*)(hrow + ((16 * (ks + 8) + 8 * hi) ^ gx8));
                acc2a = mfma32(aa, bw2[ks], acc2a);
                acc2b = mfma32(ab, bw2[ks + 8], acc2b);
            }
            float lp[4] = {0.f, 0.f, 0.f, 0.f};
            float op[4] = {0.f, 0.f, 0.f, 0.f};
#pragma unroll
            for (int r = 0; r < 16; ++r) {
                float e = __builtin_amdgcn_exp2f(acc2a[r] + acc2b[r]);
                lp[r & 3] += e;
                op[r & 3] = fmaf(e, vv[ii][r], op[r & 3]);
            }
            l_run[ii] += (lp[0] + lp[1]) + (lp[2] + lp[3]);
            o_run[ii] += (op[0] + op[1]) + (op[2] + op[3]);
        }
    }

    // ---- final merge: pure sums ----
    float L1[2], O1[2];
#pragma unroll
    for (int ii = 0; ii < 2; ++ii) {
        L1[ii] = l_run[ii] + __shfl_xor(l_run[ii], 32);
        O1[ii] = o_run[ii] + __shfl_xor(o_run[ii], 32);
        if (rt == 1 && hi == 0) {
            mrg_s[ii][ct][l31][0] = L1[ii];
            mrg_s[ii][ct][l31][1] = O1[ii];
        }
    }
    __syncthreads();
    if (rt == 0 && hi == 0) {
#pragma unroll
        for (int ii = 0; ii < 2; ++ii) {
            float L = L1[ii] + mrg_s[ii][ct][l31][0];
            float O = O1[ii] + mrg_s[ii][ct][l31][1];
            out[((size_t)b * D_ + dcol2) * N_ + i0 + ii] = O / L;
        }
    }
}

extern "C" void kernel_launch(void* const* d_in, const int* in_sizes, int n_in,
                              void* d_out, int out_size, void* d_ws, size_t ws_size,
                              hipStream_t stream) {
    const float* x    = (const float*)d_in[0];
    const float* pos  = (const float*)d_in[1];
    const float* Wqkv = (const float*)d_in[2];
    const float* bqkv = (const float*)d_in[3];
    const float* pW1  = (const float*)d_in[4];
    const float* pb1  = (const float*)d_in[5];
    const float* pW2  = (const float*)d_in[6];
    const float* pb2  = (const float*)d_in[7];
    const float* aW1  = (const float*)d_in[8];
    const float* ab1  = (const float*)d_in[9];
    const float* aW2  = (const float*)d_in[10];
    const float* ab2  = (const float*)d_in[11];
    float* out = (float*)d_out;

    float* q    = (float*)d_ws;            // 262144 f32
    float* k    = q  + B_ * N_ * D_;       // 262144 f32
    float* qa   = k  + B_ * N_ * D_;       // 524288 f32
    float* posw = qa + B_ * N_ * 256;      // 131072 f32
    float* cvec = posw + B_ * N_ * 64;     // 256 f32
    short* kab_t = (short*)(cvec + 256);   // 524288 bf16 (16x16-tiled)
    short* vb_t  = kab_t + B_ * N_ * 256;  // 262144 bf16 (32x32-tiled, +pb2)
    __hip_bfloat16* aW2T = (__hip_bfloat16*)(vb_t + B_ * N_ * D_);  // 32768
    __hip_bfloat16* pW2T = aW2T + 128 * 256;                        // 8192
    __hip_bfloat16* W12T = pW2T + 128 * 64;                         // 16384

    hipLaunchKernelGGL(prep_misc_kernel, dim3(448), dim3(256), 0, stream,
                       aW1, aW2, pW2, pb2, ab1, pos, pW1, x, Wqkv, bqkv,
                       aW2T, pW2T, W12T, cvec, posw, q, k, vb_t);
    hipLaunchKernelGGL(qka_kernel, dim3(256), dim3(256), 0, stream,
                       q, k, aW1, qa, kab_t);
    hipLaunchKernelGGL(fused_attn_kernel, dim3(1024), dim3(512), 0, stream,
                       qa, kab_t, vb_t, posw, pb1, pW2T, W12T, cvec, aW2T, out);
}